// Round 1
// 404.292 us; speedup vs baseline: 1.0267x; 1.0267x over previous
//
#include <hip/hip_runtime.h>
#include <stdint.h>
#include <stddef.h>

// out[M,N] = clip(x,±6)[M,K] @ (W_i8[N,K]*scale[N])^T + bias[N]
// M=8192, N=4096, K=4096.
// Round 5: 256x256 tile, 8 waves, ring-4 LDS K-pipeline (BK=64 i8, 128 KB LDS),
// counted s_waitcnt vmcnt(8) (never 0 in main loop), 1 barrier per K-tile,
// s_setprio(1) around the 16-MFMA cluster. Source-side XOR swizzle:
// slot = row*4 + (chunk ^ ((row>>1)&3)) -> 8 consecutive rows cover all 32 banks.

#define M_DIM 8192
#define N_DIM 4096
#define K_DIM 4096
#define ACT_CLIP 6.0f

#define BM 256
#define BN 256
#define BKI 64                 // i8 K-elements per K-tile (64 B/row)
#define NKT (K_DIM / BKI)      // 64 K-tiles
#define TILE_LDS 32768         // A 16KB + B 16KB per K-tile buffer
#define RING 4                 // 4 buffers = 128 KB

typedef __attribute__((ext_vector_type(4))) int i32x4;
typedef __attribute__((ext_vector_type(16))) int i32x16;

// async global->LDS, 16B/lane; LDS dest is wave-uniform base + lane*16.
__device__ __forceinline__ void async_load16(const void* g, void* l) {
    __builtin_amdgcn_global_load_lds(
        (const __attribute__((address_space(1))) void*)g,
        (__attribute__((address_space(3))) void*)l, 16, 0, 0);
}

// ---------------------------------------------------------------------------
// Prepass 1: per-row int8 quantization of clip(x). One block per row (K=4096).
__global__ __launch_bounds__(256) void quant_x_kernel(
    const float* __restrict__ x, int8_t* __restrict__ xq,
    float* __restrict__ rowscale) {
    const int row = blockIdx.x;
    const int tid = threadIdx.x;
    const float4* xr = (const float4*)(x + (size_t)row * K_DIM);
    float4 v[4];
    float mx = 0.f;
#pragma unroll
    for (int c = 0; c < 4; ++c) {
        float4 a = xr[c * 256 + tid];
        a.x = fminf(ACT_CLIP, fmaxf(-ACT_CLIP, a.x));
        a.y = fminf(ACT_CLIP, fmaxf(-ACT_CLIP, a.y));
        a.z = fminf(ACT_CLIP, fmaxf(-ACT_CLIP, a.z));
        a.w = fminf(ACT_CLIP, fmaxf(-ACT_CLIP, a.w));
        v[c] = a;
        mx = fmaxf(mx, fmaxf(fmaxf(fabsf(a.x), fabsf(a.y)),
                             fmaxf(fabsf(a.z), fabsf(a.w))));
    }
#pragma unroll
    for (int off = 32; off >= 1; off >>= 1)
        mx = fmaxf(mx, __shfl_xor(mx, off, 64));
    __shared__ float wmax[4];
    if ((tid & 63) == 0) wmax[tid >> 6] = mx;
    __syncthreads();
    mx = fmaxf(fmaxf(wmax[0], wmax[1]), fmaxf(wmax[2], wmax[3]));
    mx = fmaxf(mx, 1e-20f);
    const float inv = 127.f / mx;
    if (tid == 0) rowscale[row] = mx * (1.f / 127.f);
    int* out = (int*)(xq + (size_t)row * K_DIM);
#pragma unroll
    for (int c = 0; c < 4; ++c) {
        int b0 = (int)rintf(v[c].x * inv);
        int b1 = (int)rintf(v[c].y * inv);
        int b2 = (int)rintf(v[c].z * inv);
        int b3 = (int)rintf(v[c].w * inv);
        out[c * 256 + tid] =
            (b0 & 255) | ((b1 & 255) << 8) | ((b2 & 255) << 16) | ((b3 & 255) << 24);
    }
}

// ---------------------------------------------------------------------------
// Prepass 2: pack weights (int8 values in int32 storage) -> int8. 16/thread.
__global__ __launch_bounds__(256) void pack_w_kernel(
    const int* __restrict__ w, int8_t* __restrict__ wq) {
    size_t idx = (size_t)blockIdx.x * blockDim.x + threadIdx.x;  // 16 ints
    const int4* w4 = (const int4*)w;
    int r[4];
#pragma unroll
    for (int j = 0; j < 4; ++j) {
        int4 a = w4[idx * 4 + j];
        r[j] = (a.x & 255) | ((a.y & 255) << 8) | ((a.z & 255) << 16) | ((a.w & 255) << 24);
    }
    ((int4*)wq)[idx] = make_int4(r[0], r[1], r[2], r[3]);
}

// ---------------------------------------------------------------------------
// GEMM: dot_i32[M,N] = xq[M,K] @ wq[N,K]^T ; out = dot*(rowscale[m]*scale[n])+bias[n]
// 256x256 tile, BK=64, 512 threads = 8 waves (2M x 4N), 128x64 per wave
// (4x2 of 32x32). Ring-4 K-tile pipeline, lead-2 prefetch.
__global__ __launch_bounds__(512, 2) void gemm_i8_kernel(
    const int8_t* __restrict__ A, const int8_t* __restrict__ Bw,
    const float* __restrict__ rowscale, const float* __restrict__ scale,
    const float* __restrict__ bias, float* __restrict__ out) {
    extern __shared__ __align__(16) int8_t smem[];  // RING * 32 KB

    const int tid = threadIdx.x;
    const int wave = tid >> 6;
    const int lane = tid & 63;
    const int l31 = lane & 31;
    const int hi = lane >> 5;
    const int m0 = blockIdx.y * BM;
    const int n0 = blockIdx.x * BN;
    const int wm = (wave >> 2) * 128;  // wave's A-row base within tile
    const int wn = (wave & 3) * 64;    // wave's B-row base within tile

    // ---- staging setup -----------------------------------------------------
    // Per K-tile buffer: A = slots 0..1023 (16B each), B = slots at +16KB.
    // slot = row*4 + (chunk ^ ((row>>1)&3)); inverse (content of slot s):
    //   row = s>>2, chunk = (s&3) ^ ((row>>1)&3).
    // Thread stages A slots {tid, tid+512} and B slots {tid, tid+512}.
    const int8_t* ga[2];
    const int8_t* gb[2];
    int lbA[2], lbB[2];  // wave-uniform LDS byte bases for the 4 stage instrs
#pragma unroll
    for (int j = 0; j < 2; ++j) {
        const int s = tid + 512 * j;
        const int row = s >> 2;
        const int c = (s & 3) ^ ((row >> 1) & 3);
        ga[j] = A + (size_t)(m0 + row) * K_DIM + c * 16;
        gb[j] = Bw + (size_t)(n0 + row) * K_DIM + c * 16;
        lbA[j] = (wave * 64 + 512 * j) * 16;
        lbB[j] = 16384 + (wave * 64 + 512 * j) * 16;
    }

    // stage the NEXT K-tile at the current ga/gb position into ring buffer b
    auto STAGE = [&](int b) {
        int8_t* buf = smem + b * TILE_LDS;
#pragma unroll
        for (int j = 0; j < 2; ++j) async_load16(ga[j], buf + lbA[j]);
#pragma unroll
        for (int j = 0; j < 2; ++j) async_load16(gb[j], buf + lbB[j]);
#pragma unroll
        for (int j = 0; j < 2; ++j) { ga[j] += BKI; gb[j] += BKI; }
    };

    // ---- fragment read offsets (swizzled), relative to buffer base ---------
    // A-frag for 32x32x32: row = wm + mt*32 + l31, byte chunk = ks*2 + hi.
    int aoff[4][2], boff[2][2];
#pragma unroll
    for (int mt = 0; mt < 4; ++mt)
#pragma unroll
        for (int ks = 0; ks < 2; ++ks) {
            const int row = wm + mt * 32 + l31;
            const int c = ks * 2 + hi;
            aoff[mt][ks] = (row * 4 + (c ^ ((row >> 1) & 3))) * 16;
        }
#pragma unroll
    for (int nt = 0; nt < 2; ++nt)
#pragma unroll
        for (int ks = 0; ks < 2; ++ks) {
            const int row = wn + nt * 32 + l31;
            const int c = ks * 2 + hi;
            boff[nt][ks] = 16384 + (row * 4 + (c ^ ((row >> 1) & 3))) * 16;
        }

    i32x16 acc[4][2] = {};

    // ---- prologue: fill pipeline 2 K-tiles deep ----------------------------
    STAGE(0);
    STAGE(1);

    // ---- main loop: 1 barrier + 1 counted vmcnt per K-tile -----------------
    for (int t = 0; t < NKT; ++t) {
        if (t + 2 < NKT) STAGE((t + 2) & 3);
        // tile t's 4 loads are the oldest; tiles t+1,t+2 (8 loads) stay in flight
        if (t < NKT - 2) {
            asm volatile("s_waitcnt vmcnt(8)" ::: "memory");
        } else if (t == NKT - 2) {
            asm volatile("s_waitcnt vmcnt(4)" ::: "memory");
        } else {
            asm volatile("s_waitcnt vmcnt(0)" ::: "memory");
        }
        asm volatile("s_barrier" ::: "memory");

        const int8_t* buf = smem + (t & 3) * TILE_LDS;
#pragma unroll
        for (int ks = 0; ks < 2; ++ks) {
            i32x4 af[4], bf[2];
#pragma unroll
            for (int mt = 0; mt < 4; ++mt)
                af[mt] = *(const i32x4*)(buf + aoff[mt][ks]);
#pragma unroll
            for (int nt = 0; nt < 2; ++nt)
                bf[nt] = *(const i32x4*)(buf + boff[nt][ks]);
            __builtin_amdgcn_s_setprio(1);
#pragma unroll
            for (int mt = 0; mt < 4; ++mt)
#pragma unroll
                for (int nt = 0; nt < 2; ++nt)
                    acc[mt][nt] = __builtin_amdgcn_mfma_i32_32x32x32_i8(
                        af[mt], bf[nt], acc[mt][nt], 0, 0, 0);
            __builtin_amdgcn_s_setprio(0);
        }
    }

    // ---- epilogue: C/D layout col=lane&31, row=(reg&3)+8*(reg>>2)+4*hi -----
    const int ccol = l31;
#pragma unroll
    for (int mt = 0; mt < 4; ++mt) {
        const int gmb = m0 + wm + mt * 32;
        float rs[16];
#pragma unroll
        for (int r = 0; r < 16; ++r)
            rs[r] = rowscale[gmb + (r & 3) + 4 * hi + 8 * (r >> 2)];
#pragma unroll
        for (int nt = 0; nt < 2; ++nt) {
            const int gn = n0 + wn + nt * 32 + ccol;
            const float sc = scale[gn];
            const float bi = bias[gn];
            float* op = out + (size_t)gmb * N_DIM + gn;
#pragma unroll
            for (int r = 0; r < 16; ++r) {
                const int grow = (r & 3) + 4 * hi + 8 * (r >> 2);
                op[(size_t)grow * N_DIM] =
                    fmaf((float)acc[mt][nt][r], rs[r] * sc, bi);
            }
        }
    }
}

// ---------------------------------------------------------------------------
extern "C" void kernel_launch(void* const* d_in, const int* in_sizes, int n_in,
                              void* d_out, int out_size, void* d_ws, size_t ws_size,
                              hipStream_t stream) {
    const float* x = (const float*)d_in[0];
    const int* w_i8 = (const int*)d_in[1];
    const float* w_scale = (const float*)d_in[2];
    const float* bias = (const float*)d_in[3];
    float* out = (float*)d_out;

    int8_t* xq = (int8_t*)d_ws;                                   // 33.5 MB
    int8_t* wq = (int8_t*)d_ws + (size_t)M_DIM * K_DIM;           // 16.8 MB
    float* rowscale = (float*)((int8_t*)d_ws + (size_t)M_DIM * K_DIM
                               + (size_t)N_DIM * K_DIM);          // 32 KB

    static bool attr_done = false;
    if (!attr_done) {
        hipFuncSetAttribute((const void*)gemm_i8_kernel,
                            hipFuncAttributeMaxDynamicSharedMemorySize,
                            RING * TILE_LDS);
        attr_done = true;
    }

    quant_x_kernel<<<M_DIM, 256, 0, stream>>>(x, xq, rowscale);
    pack_w_kernel<<<(size_t)N_DIM * K_DIM / (16 * 256), 256, 0, stream>>>(w_i8, wq);

    dim3 grid(N_DIM / BN, M_DIM / BM);  // (16, 32) = 512 blocks, 2 rounds/CU
    gemm_i8_kernel<<<grid, 512, RING * TILE_LDS, stream>>>(
        xq, wq, rowscale, w_scale, bias, out);
}

// Round 2
// 395.034 us; speedup vs baseline: 1.0508x; 1.0234x over previous
//
#include <hip/hip_runtime.h>
#include <stdint.h>
#include <stddef.h>

// out[M,N] = clip(x,±6)[M,K] @ (W_i8[N,K]*scale[N])^T + bias[N]
// M=8192, N=4096, K=4096.
// Round 6: register fragment double-buffer (R0/R1) so ds_reads of the next
// half-K always fly underneath the current 8-MFMA cluster. Ring-4 LDS,
// lead-3 prefetch, vmcnt(8) counted waits, 1 barrier per K-tile (mid-tile,
// certifying tile t+1). Fused prepasses into one launch.

#define M_DIM 8192
#define N_DIM 4096
#define K_DIM 4096
#define ACT_CLIP 6.0f

#define BM 256
#define BN 256
#define BKI 64                 // i8 K-elements per K-tile (64 B/row)
#define NKT (K_DIM / BKI)      // 64 K-tiles
#define TILE_LDS 32768         // A 16KB + B 16KB per K-tile buffer
#define RING 4                 // 4 buffers = 128 KB

typedef __attribute__((ext_vector_type(4))) int i32x4;
typedef __attribute__((ext_vector_type(16))) int i32x16;

// async global->LDS, 16B/lane; LDS dest is wave-uniform base + lane*16.
__device__ __forceinline__ void async_load16(const void* g, void* l) {
    __builtin_amdgcn_global_load_lds(
        (const __attribute__((address_space(1))) void*)g,
        (__attribute__((address_space(3))) void*)l, 16, 0, 0);
}

// ---------------------------------------------------------------------------
// Fused prepass: blocks [0, M_DIM) quantize x rows; blocks [M_DIM, ...) pack w.
__global__ __launch_bounds__(256) void prep_kernel(
    const float* __restrict__ x, int8_t* __restrict__ xq,
    float* __restrict__ rowscale,
    const int* __restrict__ w, int8_t* __restrict__ wq) {
    const int tid = threadIdx.x;
    if (blockIdx.x < M_DIM) {
        // ---- per-row int8 quantization of clip(x), one block per row ----
        const int row = blockIdx.x;
        const float4* xr = (const float4*)(x + (size_t)row * K_DIM);
        float4 v[4];
        float mx = 0.f;
#pragma unroll
        for (int c = 0; c < 4; ++c) {
            float4 a = xr[c * 256 + tid];
            a.x = fminf(ACT_CLIP, fmaxf(-ACT_CLIP, a.x));
            a.y = fminf(ACT_CLIP, fmaxf(-ACT_CLIP, a.y));
            a.z = fminf(ACT_CLIP, fmaxf(-ACT_CLIP, a.z));
            a.w = fminf(ACT_CLIP, fmaxf(-ACT_CLIP, a.w));
            v[c] = a;
            mx = fmaxf(mx, fmaxf(fmaxf(fabsf(a.x), fabsf(a.y)),
                                 fmaxf(fabsf(a.z), fabsf(a.w))));
        }
#pragma unroll
        for (int off = 32; off >= 1; off >>= 1)
            mx = fmaxf(mx, __shfl_xor(mx, off, 64));
        __shared__ float wmax[4];
        if ((tid & 63) == 0) wmax[tid >> 6] = mx;
        __syncthreads();
        mx = fmaxf(fmaxf(wmax[0], wmax[1]), fmaxf(wmax[2], wmax[3]));
        mx = fmaxf(mx, 1e-20f);
        const float inv = 127.f / mx;
        if (tid == 0) rowscale[row] = mx * (1.f / 127.f);
        int* out = (int*)(xq + (size_t)row * K_DIM);
#pragma unroll
        for (int c = 0; c < 4; ++c) {
            int b0 = (int)rintf(v[c].x * inv);
            int b1 = (int)rintf(v[c].y * inv);
            int b2 = (int)rintf(v[c].z * inv);
            int b3 = (int)rintf(v[c].w * inv);
            out[c * 256 + tid] =
                (b0 & 255) | ((b1 & 255) << 8) | ((b2 & 255) << 16) | ((b3 & 255) << 24);
        }
    } else {
        // ---- pack weights (int8 values in int32 storage) -> int8, 16/thread
        size_t idx = (size_t)(blockIdx.x - M_DIM) * 256 + tid;
        const int4* w4 = (const int4*)w;
        int r[4];
#pragma unroll
        for (int j = 0; j < 4; ++j) {
            int4 a = w4[idx * 4 + j];
            r[j] = (a.x & 255) | ((a.y & 255) << 8) | ((a.z & 255) << 16) |
                   ((a.w & 255) << 24);
        }
        ((int4*)wq)[idx] = make_int4(r[0], r[1], r[2], r[3]);
    }
}

// ---------------------------------------------------------------------------
// GEMM: dot_i32[M,N] = xq[M,K] @ wq[N,K]^T ; out = dot*(rowscale[m]*scale[n])+bias[n]
// 256x256 tile, BK=64, 512 threads = 8 waves (2M x 4N), 128x64 per wave
// (4x2 of 32x32). Ring-4 K-tile pipeline, lead-3, reg-dbuf fragments.
__global__ __launch_bounds__(512, 2) void gemm_i8_kernel(
    const int8_t* __restrict__ A, const int8_t* __restrict__ Bw,
    const float* __restrict__ rowscale, const float* __restrict__ scale,
    const float* __restrict__ bias, float* __restrict__ out) {
    extern __shared__ __align__(16) int8_t smem[];  // RING * 32 KB

    const int tid = threadIdx.x;
    const int wave = tid >> 6;
    const int lane = tid & 63;
    const int l31 = lane & 31;
    const int hi = lane >> 5;
    const int m0 = blockIdx.y * BM;
    const int n0 = blockIdx.x * BN;
    const int wm = (wave >> 2) * 128;  // wave's A-row base within tile
    const int wn = (wave & 3) * 64;    // wave's B-row base within tile

    // ---- staging setup -----------------------------------------------------
    // Per K-tile buffer: A = slots 0..1023 (16B each), B at +16KB.
    // slot = row*4 + (chunk ^ ((row>>1)&3)).
    const int8_t* ga[2];
    const int8_t* gb[2];
    int lbA[2], lbB[2];
#pragma unroll
    for (int j = 0; j < 2; ++j) {
        const int s = tid + 512 * j;
        const int row = s >> 2;
        const int c = (s & 3) ^ ((row >> 1) & 3);
        ga[j] = A + (size_t)(m0 + row) * K_DIM + c * 16;
        gb[j] = Bw + (size_t)(n0 + row) * K_DIM + c * 16;
        lbA[j] = (wave * 64 + 512 * j) * 16;
        lbB[j] = 16384 + (wave * 64 + 512 * j) * 16;
    }

    auto STAGE = [&](int b) {
        int8_t* buf = smem + b * TILE_LDS;
#pragma unroll
        for (int j = 0; j < 2; ++j) async_load16(ga[j], buf + lbA[j]);
#pragma unroll
        for (int j = 0; j < 2; ++j) async_load16(gb[j], buf + lbB[j]);
#pragma unroll
        for (int j = 0; j < 2; ++j) { ga[j] += BKI; gb[j] += BKI; }
    };

    // ---- fragment read bases (swizzled). (row>>1)&3 == (l31>>1)&3 since
    // wm/mt*32/wn/nt*32 only touch bits >=5. Per (ks): one base; mt/nt via
    // +2048 immediates folded into ds_read offset.
    const int swz = (l31 >> 1) & 3;
    const int abase0 = (wm + l31) * 64 + ((0 * 2 + hi) ^ swz) * 16;
    const int abase1 = (wm + l31) * 64 + ((1 * 2 + hi) ^ swz) * 16;
    const int bbase0 = 16384 + (wn + l31) * 64 + ((0 * 2 + hi) ^ swz) * 16;
    const int bbase1 = 16384 + (wn + l31) * 64 + ((1 * 2 + hi) ^ swz) * 16;

    i32x4 a0[4], b0[2], a1[4], b1[2];
    i32x16 acc[4][2] = {};

    auto READ0 = [&](const int8_t* buf) {
#pragma unroll
        for (int mt = 0; mt < 4; ++mt)
            a0[mt] = *(const i32x4*)(buf + abase0 + mt * 2048);
#pragma unroll
        for (int nt = 0; nt < 2; ++nt)
            b0[nt] = *(const i32x4*)(buf + bbase0 + nt * 2048);
    };
    auto READ1 = [&](const int8_t* buf) {
#pragma unroll
        for (int mt = 0; mt < 4; ++mt)
            a1[mt] = *(const i32x4*)(buf + abase1 + mt * 2048);
#pragma unroll
        for (int nt = 0; nt < 2; ++nt)
            b1[nt] = *(const i32x4*)(buf + bbase1 + nt * 2048);
    };
    auto MFMA0 = [&]() {
        __builtin_amdgcn_s_setprio(1);
#pragma unroll
        for (int mt = 0; mt < 4; ++mt)
#pragma unroll
            for (int nt = 0; nt < 2; ++nt)
                acc[mt][nt] = __builtin_amdgcn_mfma_i32_32x32x32_i8(
                    a0[mt], b0[nt], acc[mt][nt], 0, 0, 0);
        __builtin_amdgcn_s_setprio(0);
    };
    auto MFMA1 = [&]() {
        __builtin_amdgcn_s_setprio(1);
#pragma unroll
        for (int mt = 0; mt < 4; ++mt)
#pragma unroll
            for (int nt = 0; nt < 2; ++nt)
                acc[mt][nt] = __builtin_amdgcn_mfma_i32_32x32x32_i8(
                    a1[mt], b1[nt], acc[mt][nt], 0, 0, 0);
        __builtin_amdgcn_s_setprio(0);
    };

    // ---- prologue: fill pipeline 3 deep, certify tile 0, preload R0 --------
    STAGE(0);
    STAGE(1);
    STAGE(2);
    asm volatile("s_waitcnt vmcnt(8)" ::: "memory");  // tile0's 4 loads done
    asm volatile("s_barrier" ::: "memory");
    READ0(smem);  // tile 0, ks=0

    // ---- main loop: t = 0 .. NKT-2 ------------------------------------------
    for (int t = 0; t < NKT - 1; ++t) {
        if (t + 3 < NKT) STAGE((t + 3) & 3);
        READ1(smem + (t & 3) * TILE_LDS);  // ks=1 of tile t, flies under MFMA0
        MFMA0();                           // ks=0 of tile t (R0 preloaded)
        // certify tile t+1: in-flight = {t+1,t+2,t+3}(12) / {t+2,t+3}(8) / {t+3}(4)
        if (t < NKT - 3) {
            asm volatile("s_waitcnt vmcnt(8)" ::: "memory");
        } else if (t == NKT - 3) {
            asm volatile("s_waitcnt vmcnt(4)" ::: "memory");
        } else {
            asm volatile("s_waitcnt vmcnt(0)" ::: "memory");
        }
        asm volatile("s_barrier" ::: "memory");
        __builtin_amdgcn_sched_barrier(0);
        READ0(smem + ((t + 1) & 3) * TILE_LDS);  // ks=0 of t+1, flies under MFMA1
        MFMA1();                                 // ks=1 of tile t
    }
    // ---- tail: tile NKT-1 (certified by the t=NKT-2 barrier) ---------------
    READ1(smem + ((NKT - 1) & 3) * TILE_LDS);
    MFMA0();
    MFMA1();

    // ---- epilogue: C/D layout col=lane&31, row=(reg&3)+8*(reg>>2)+4*hi -----
    const int ccol = l31;
#pragma unroll
    for (int mt = 0; mt < 4; ++mt) {
        const int gmb = m0 + wm + mt * 32;
        float rs[16];
#pragma unroll
        for (int r = 0; r < 16; ++r)
            rs[r] = rowscale[gmb + (r & 3) + 4 * hi + 8 * (r >> 2)];
#pragma unroll
        for (int nt = 0; nt < 2; ++nt) {
            const int gn = n0 + wn + nt * 32 + ccol;
            const float sc = scale[gn];
            const float bi = bias[gn];
            float* op = out + (size_t)gmb * N_DIM + gn;
#pragma unroll
            for (int r = 0; r < 16; ++r) {
                const int grow = (r & 3) + 4 * hi + 8 * (r >> 2);
                op[(size_t)grow * N_DIM] =
                    fmaf((float)acc[mt][nt][r], rs[r] * sc, bi);
            }
        }
    }
}

// ---------------------------------------------------------------------------
extern "C" void kernel_launch(void* const* d_in, const int* in_sizes, int n_in,
                              void* d_out, int out_size, void* d_ws, size_t ws_size,
                              hipStream_t stream) {
    const float* x = (const float*)d_in[0];
    const int* w_i8 = (const int*)d_in[1];
    const float* w_scale = (const float*)d_in[2];
    const float* bias = (const float*)d_in[3];
    float* out = (float*)d_out;

    int8_t* xq = (int8_t*)d_ws;                                   // 33.5 MB
    int8_t* wq = (int8_t*)d_ws + (size_t)M_DIM * K_DIM;           // 16.8 MB
    float* rowscale = (float*)((int8_t*)d_ws + (size_t)M_DIM * K_DIM
                               + (size_t)N_DIM * K_DIM);          // 32 KB

    static bool attr_done = false;
    if (!attr_done) {
        hipFuncSetAttribute((const void*)gemm_i8_kernel,
                            hipFuncAttributeMaxDynamicSharedMemorySize,
                            RING * TILE_LDS);
        attr_done = true;
    }

    const int pack_blocks = (int)((size_t)N_DIM * K_DIM / (16 * 256));  // 4096
    prep_kernel<<<M_DIM + pack_blocks, 256, 0, stream>>>(x, xq, rowscale, w_i8, wq);

    dim3 grid(N_DIM / BN, M_DIM / BM);  // (16, 32) = 512 blocks, 2 rounds/CU
    gemm_i8_kernel<<<grid, 512, RING * TILE_LDS, stream>>>(
        xq, wq, rowscale, w_scale, bias, out);
}